// Round 15
// baseline (72.032 us; speedup 1.0000x reference)
//
#include <hip/hip_runtime.h>

#define IC 128
#define OC 256
#define RR 64
#define CCOLS 64
#define HO 62
#define WO 62
#define NB 16

// Fragment-major dense bf16 weights:
//   W9Tf[chunk][g][lane][elem], chunk = kp*8+ck (72), g = oc>>5 (8 groups),
//   lane = (oc&31) + 32*khalf (64), elem = c&7 (8 bf16 = 16 B).
// A wave's A-fragment load for one chunk/group is base + lane*16: 1 KB
// contiguous (coalesced; the R8 win).
#define W9T_BYTES (9 * OC * IC * 2)   // 589824
#define CHUNK_STRIDE 8192             // 8 ocgroups * 64 lanes * 16 B
#define LDSROW 16384                  // one image row: 64 x * 256 B

typedef __bf16 bf16x8 __attribute__((ext_vector_type(8)));
typedef float f32x16 __attribute__((ext_vector_type(16)));

__device__ __forceinline__ unsigned short f2bf(float f) {
    unsigned u = __builtin_bit_cast(unsigned, f);
    u += 0x7FFFu + ((u >> 16) & 1u);   // round-to-nearest-even
    return (unsigned short)(u >> 16);
}

// prep: blocks 0..OC-1 scatter weights; block OC densifies the bias.
__global__ void prep_weights(const float* __restrict__ wv,
                             const int* __restrict__ iwi,
                             const int* __restrict__ flen,
                             const int* __restrict__ sp,
                             unsigned char* __restrict__ W9Tf,
                             const int* __restrict__ bias_index,
                             const float* __restrict__ bias_value,
                             float* __restrict__ bias_dense, int nbias) {
    if (blockIdx.x == OC) {
        int t = threadIdx.x;
        if (t < OC) bias_dense[t] = 0.f;
        __syncthreads();
        if (t < nbias) atomicAdd(&bias_dense[bias_index[t]], bias_value[t]);
        return;
    }
    const int oc = blockIdx.x;
    const int s = sp[oc];
    const int n = flen[oc];
    const int g = oc >> 5;
    for (int t = threadIdx.x; t < n; t += blockDim.x) {
        const int ix = iwi[s + t];          // c*4096 + ky*64 + kx
        const int c = ix >> 12;
        const int rem = ix & 4095;
        const int ky = rem >> 6, kx = rem & 63;
        const int kp = ky * 3 + kx;
        const int ck = c >> 4;
        const int khalf = (c >> 3) & 1;
        const int lane = (oc & 31) + (khalf << 5);
        const size_t off = (size_t)(kp * 8 + ck) * CHUNK_STRIDE +
                           g * 1024 + lane * 16 + (c & 7) * 2;
        *(unsigned short*)(W9Tf + off) = f2bf(wv[s + t]);
    }
}

// Block = one output row (b, y) x all 256 oc. 512 threads = 8 waves.
// Wave w: 32 oc (one 32x32 m-frag) x 64 x (2 n-tiles). R8 champion
// structure; the one lever that has moved this kernel is resident waves
// (R8 16/CU = 64us beats every 8-12/CU variant at 75-100us). 48 KB LDS
// allows 3 blocks/CU = 24 waves/CU; the blocker was regs (R8: 88/wave,
// 6 waves/SIMD needs <=85). Trim: A-prefetch 3-deep, B cur+next, and
// launch_bounds(512,3) pins the 85-reg tier. Demand ~77 -> no spill.
__global__ __launch_bounds__(512, 3) void conv_mfma(
    const float* __restrict__ images,
    const unsigned char* __restrict__ W9Tf,
    const float* __restrict__ bias_dense,
    float* __restrict__ out)
{
    const int y = blockIdx.x;
    const int b = blockIdx.y;
    const int t = threadIdx.x;
    const int w = t >> 6;
    const int l = t & 63;
    const int lm = l & 31;            // m-row / n-col within frag
    const int lhi16 = (l >> 5) * 16;  // k-half byte offset

    __shared__ unsigned char lds[3 * LDSROW];   // 49152 B

    const float* __restrict__ imgb = images + (size_t)b * (IC * RR * CCOLS);

    // ---- stage 3 image rows, fp32 -> bf16, [x][c] with XOR swizzle ----
    {
        const int xs = t & 63;
        const int oct = t >> 6;             // 0..7
        const int swz = (xs & 7) << 4;
        #pragma unroll
        for (int krow = 0; krow < 3; ++krow) {
            #pragma unroll
            for (int h = 0; h < 2; ++h) {
                const int c0 = (oct + 8 * h) * 8;   // octet base channel
                const float* __restrict__ p =
                    imgb + (size_t)c0 * (RR * CCOLS) + (y + krow) * CCOLS + xs;
                unsigned v0, v1, v2, v3;
                v0 = (unsigned)f2bf(p[0])              | ((unsigned)f2bf(p[RR * CCOLS])     << 16);
                v1 = (unsigned)f2bf(p[2 * RR * CCOLS]) | ((unsigned)f2bf(p[3 * RR * CCOLS]) << 16);
                v2 = (unsigned)f2bf(p[4 * RR * CCOLS]) | ((unsigned)f2bf(p[5 * RR * CCOLS]) << 16);
                v3 = (unsigned)f2bf(p[6 * RR * CCOLS]) | ((unsigned)f2bf(p[7 * RR * CCOLS]) << 16);
                *(uint4*)(lds + krow * LDSROW + xs * 256 + ((c0 * 2) ^ swz)) =
                    make_uint4(v0, v1, v2, v3);
            }
        }
    }

    // lane's coalesced A base
    const unsigned char* __restrict__ pA = W9Tf + w * 1024 + l * 16;

    // prologue: prefetch A chunks 0..2 (global only, no LDS hazard)
    bf16x8 aC  = *(const bf16x8*)(pA);
    bf16x8 aN1 = *(const bf16x8*)(pA + CHUNK_STRIDE);
    bf16x8 aN2 = *(const bf16x8*)(pA + 2 * CHUNK_STRIDE);

    __syncthreads();

    // B reader for chunk idx (compile-time ky/kx/ck under full unroll)
    auto readB = [&](int idx, bf16x8& b0, bf16x8& b1) {
        const int kp = idx >> 3, ck = idx & 7;
        const int ky = kp / 3, kx = kp % 3;
        const int x0 = lm + kx;                      // <= 33, in-bounds
        int x1 = 32 + lm + kx;
        x1 = x1 > 63 ? 63 : x1;   // pad lanes: dup col 63 (output discarded)
        const unsigned char* __restrict__ row = lds + ky * LDSROW;
        const int pb0 = (x0 * 256 + (lhi16 ^ ((x0 & 7) << 4))) ^ (ck * 32);
        const int pb1 = (x1 * 256 + (lhi16 ^ ((x1 & 7) << 4))) ^ (ck * 32);
        b0 = *(const bf16x8*)(row + pb0);
        b1 = *(const bf16x8*)(row + pb1);
    };

    f32x16 acc0 = {}, acc1 = {};
    bf16x8 b0c, b1c;
    readB(0, b0c, b1c);

    #pragma unroll
    for (int idx = 0; idx < 72; ++idx) {
        // prefetch A chunk idx+3 (coalesced 1 KB global load)
        bf16x8 aN3;
        if (idx + 3 < 72)
            aN3 = *(const bf16x8*)(pA + (size_t)(idx + 3) * CHUNK_STRIDE);
        // prefetch B chunk idx+1 (2x ds_read_b128, covered by MFMAs below)
        bf16x8 b0n, b1n;
        if (idx + 1 < 72) readB(idx + 1, b0n, b1n);

        acc0 = __builtin_amdgcn_mfma_f32_32x32x16_bf16(aC, b0c, acc0, 0, 0, 0);
        acc1 = __builtin_amdgcn_mfma_f32_32x32x16_bf16(aC, b1c, acc1, 0, 0, 0);

        aC = aN1; aN1 = aN2;                         // SSA-renamed, no copies
        if (idx + 3 < 72) aN2 = aN3;
        if (idx + 1 < 72) { b0c = b0n; b1c = b1n; }
    }

    // ---- epilogue: bias + store ----
    // C/D 32x32: col = lane&31, row = (reg&3) + 8*(reg>>2) + 4*(lane>>5)
    const int ocw = 32 * w;
    #pragma unroll
    for (int r = 0; r < 16; ++r) {
        const int oc = ocw + (r & 3) + 8 * (r >> 2) + (lhi16 >> 2);
        const float bv = bias_dense[oc];
        const size_t ob = (((size_t)b * OC + oc) * HO + y) * WO;
        out[ob + lm] = acc0[r] + bv;             // x = lm < 62 always
        if (lm < 30)
            out[ob + 32 + lm] = acc1[r] + bv;    // x = 32+lm, clip at 62
    }
}

extern "C" void kernel_launch(void* const* d_in, const int* in_sizes, int n_in,
                              void* d_out, int out_size, void* d_ws, size_t ws_size,
                              hipStream_t stream) {
    const float* images             = (const float*)d_in[0];
    const float* weight_value       = (const float*)d_in[1];
    const int*   image_weight_index = (const int*)d_in[2];
    const int*   filter_lengths     = (const int*)d_in[3];
    const int*   start_points       = (const int*)d_in[4];
    const int*   bias_index         = (const int*)d_in[5];
    const float* bias_value         = (const float*)d_in[6];
    float* out = (float*)d_out;

    unsigned char* W9Tf = (unsigned char*)d_ws;
    float* bias_dense = (float*)((char*)d_ws + W9T_BYTES);

    hipMemsetAsync(d_ws, 0, W9T_BYTES, stream);
    prep_weights<<<OC + 1, 256, 0, stream>>>(weight_value, image_weight_index,
                                             filter_lengths, start_points, W9Tf,
                                             bias_index, bias_value, bias_dense,
                                             in_sizes[5]);

    dim3 grid(HO, NB);
    conv_mfma<<<grid, 512, 0, stream>>>(images, W9Tf, bias_dense, out);
}